// Round 5
// baseline (9.723 us; speedup 1.0000x reference)
//
#include <hip/hip_runtime.h>

#define NQ    12
#define BATCH 1024

typedef float v2 __attribute__((ext_vector_type(2)));
typedef float v4 __attribute__((ext_vector_type(4)));

// tangent-form packed RY on v2-array bit P (32 entries): pairs (m, m|2^P)
template<int P>
__device__ __forceinline__ void ryp32_t(v2 A[32], float t) {
#pragma unroll
    for (int m = 0; m < 32; ++m) {
        if ((m & (1 << P)) == 0) {
            const int j = m | (1 << P);
            const v2 Ai = A[m], Aj = A[j];
            A[m] = Ai - t * Aj;      // 1 pk_fma
            A[j] = Aj + t * Ai;      // 1 pk_fma
        }
    }
}

// tangent-form RY on the within-v2 bit
__device__ __forceinline__ void ry032_t(v2 A[32], float t) {
    const v2 tv = v2{-t, t};
#pragma unroll
    for (int m = 0; m < 32; ++m) {
        const v2 sw = v2{A[m].y, A[m].x};
        A[m] = A[m] + tv * sw;
    }
}

__device__ __forceinline__ float rdlane(float v, int lane) {
    return __uint_as_float(__builtin_amdgcn_readlane(__float_as_uint(v), lane));
}

// DPP quad_perm cross-lane (VALU pipe): 0xB1 = xor1, 0x4E = xor2
template<int CTRL>
__device__ __forceinline__ float dppx(float v) {
    return __int_as_float(__builtin_amdgcn_mov_dpp(__float_as_int(v), CTRL, 0xF, 0xF, true));
}
// ds_swizzle BitMode: offset = (xor<<10) | 0x1F
template<int PAT>
__device__ __forceinline__ float swz(float v) {
    return __int_as_float(__builtin_amdgcn_ds_swizzle(__float_as_int(v), PAT));
}

__global__ __launch_bounds__(64)
void qc_kernel(const float* __restrict__ x, const float* __restrict__ th,
               float* __restrict__ out) {
    // one batch element per 64-thread block (ONE wave): no real barriers,
    // no cross-wave folds. Transpose buffer col-major: addr = col*68 + row,
    // col (64) = qubits 0..5, row (64) = qubits 6..11; stride 68 = 64+4 pad.
    __shared__ __attribute__((aligned(16))) float buf[64 * 68];

    const int b = blockIdx.x;
    const int l = threadIdx.x;            // 0..63, single wave
    const float* xb = x + b * NQ;

    // ---- lane-parallel sincos (verified R0) ----
    const int q_ = l & 31;
    float ang;
    if (l & 32) ang = (q_ < 12) ? 0.5f * th[NQ + q_] : 0.0f;
    else        { const int m_ = (q_ < 12) ? q_ : 11; ang = 0.5f * (xb[m_] + th[m_]); }
    float sv_, cv_;
    __sincosf(ang, &sv_, &cv_);
    const float tl = __fdividef(sv_, cv_);   // tan(ang); valid where used (lanes 32..43)

    // C = prod_{q=0..11} cos(th1_q/2): product tree over lanes 32..47
    float pt = cv_;
    pt *= dppx<0xB1>(pt);        // xor 1
    pt *= dppx<0x4E>(pt);        // xor 2
    pt *= swz<0x101F>(pt);       // xor 4
    pt *= swz<0x201F>(pt);       // xor 8
    const float C = rdlane(pt, 32);

    float c_[NQ], s_[NQ], t1[NQ];
#pragma unroll
    for (int q = 0; q < NQ; ++q) {
        c_[q] = rdlane(cv_, q);
        s_[q] = rdlane(sv_, q);
        t1[q] = rdlane(tl, 32 + q);
    }

    // ---- POST-ring#1 state, layout L1': reg bits r0..r5 = qubits 0..5,
    //      lane bits l0..l5 = qubits 6..11.
    // Ring-1 inverse: y_q = z_q^z_{q-1} (q>=2), y1 = z1^z0^z11, y0 = z0^z11.
    const int l0=l&1, l1=(l>>1)&1, l2=(l>>2)&1, l3=(l>>3)&1, l4=(l>>4)&1, l5=(l>>5)&1;
    float GL = ((l1^l0) ? s_[7] : c_[7]) * ((l2^l1) ? s_[8] : c_[8]);
    GL *= ((l3^l2) ? s_[9] : c_[9]) * ((l4^l3) ? s_[10] : c_[10]);
    GL *= ((l5^l4) ? s_[11] : c_[11]) * C;          // q7..q11 factors + deferred C
    const float GL0 = GL * (l0 ? s_[6] : c_[6]);    // q6 factor, entries r5=0 (sel=l0)
    const float GL1 = GL * (l0 ? c_[6] : s_[6]);    // entries r5=1 (sel=l0^1)

    const float f0_0 = l5 ? s_[0] : c_[0], f0_1 = l5 ? c_[0] : s_[0];   // q0: r0^l5
    const float f1_0 = l5 ? s_[1] : c_[1], f1_1 = l5 ? c_[1] : s_[1];   // q1: r1^r0^l5

    v2 A[32];
    A[0] = v2{f0_0 * f1_0, f0_1 * f1_1};
    A[1] = v2{f0_0 * f1_1, f0_1 * f1_0};
#pragma unroll
    for (int k = 2; k < 5; ++k) {                    // q2..q4: sel = r_k ^ r_{k-1}
#pragma unroll
        for (int m = 0; m < (1 << (k - 1)); ++m) {
            const int bp = (m >> (k - 2)) & 1;
            A[m | (1 << (k - 1))] = A[m] * (bp ? c_[k] : s_[k]);
            A[m]                  = A[m] * (bp ? s_[k] : c_[k]);
        }
    }
    // k=5 (q5) with GL0/GL1 merged
    {
        const float cH = c_[5] * GL1, sH = s_[5] * GL1;
        const float cL = c_[5] * GL0, sL = s_[5] * GL0;
#pragma unroll
        for (int m = 0; m < 16; ++m) {
            const int bp = (m >> 3) & 1;             // r4
            A[m | 16] = A[m] * (bp ? cH : sH);
            A[m]      = A[m] * (bp ? sL : cL);
        }
    }

    // ---- layer-1 phase 1: qubits 0..5 on reg bits (tangent form) ----
    ry032_t(A, t1[0]);
    ryp32_t<0>(A, t1[1]);
    ryp32_t<1>(A, t1[2]);
    ryp32_t<2>(A, t1[3]);
    ryp32_t<3>(A, t1[4]);
    ryp32_t<4>(A, t1[5]);

    // ---- transpose write: col = 2m+c (q0..q5), row = l (q6..q11) ----
    {
        float* wp = &buf[l];
#pragma unroll
        for (int m = 0; m < 32; ++m) {
            wp[(2*m)   * 68] = A[m].x;
            wp[(2*m+1) * 68] = A[m].y;
        }
    }
    __syncthreads();   // single-wave block: compiles to waitcnt + trivial barrier

    // ---- transpose read: 16 x ds_read_b128, pure (no folds needed) ----
    {
        const float* rp = &buf[l * 68];
#pragma unroll
        for (int k = 0; k < 16; ++k) {
            const v4 t = *reinterpret_cast<const v4*>(rp + 4*k);
            A[2*k]   = v2{t.x, t.y};
            A[2*k+1] = v2{t.z, t.w};
        }
    }
    // layout L2': reg bits r0..r5 = qubits 6..11, lane bits = qubits 0..5

    // ---- layer-1 phase 2: qubits 6..11 on reg bits (tangent form) ----
    ry032_t(A, t1[6]);
    ryp32_t<0>(A, t1[7]);
    ryp32_t<1>(A, t1[8]);
    ryp32_t<2>(A, t1[9]);
    ryp32_t<3>(A, t1[10]);
    ryp32_t<4>(A, t1[11]);

    // ---- measurement (ring #2 absorbed): Z_q = E[(-1)^{z0..zq}], Z0 = E[(-1)^{z1..z11}]
    // reg signs: r0=z6 (v2 bit), r1..r5 = z7..z11 (A-index bits)
#pragma unroll
    for (int m = 0; m < 32; ++m) A[m] *= A[m];

    v2 e[16], f[16];
#pragma unroll
    for (int i = 0; i < 16; ++i) { e[i] = A[2*i] + A[2*i+1]; f[i] = A[2*i] - A[2*i+1]; }
    const v2 se = (((e[0]+e[1])+(e[2]+e[3])) + ((e[4]+e[5])+(e[6]+e[7])))
                + (((e[8]+e[9])+(e[10]+e[11])) + ((e[12]+e[13])+(e[14]+e[15])));
    v2 fp[8], ff[8];
#pragma unroll
    for (int j = 0; j < 8; ++j) { fp[j] = f[2*j] + f[2*j+1]; ff[j] = f[2*j] - f[2*j+1]; }
    const v2 sf1 = ((fp[0]+fp[1])+(fp[2]+fp[3])) + ((fp[4]+fp[5])+(fp[6]+fp[7]));
    v2 fa[4], fff[4];
#pragma unroll
    for (int k = 0; k < 4; ++k) { fa[k] = ff[2*k] + ff[2*k+1]; fff[k] = ff[2*k] - ff[2*k+1]; }
    const v2 sff  = (fa[0]+fa[1]) + (fa[2]+fa[3]);
    const v2 sfff = (fff[0]+fff[1]) + (fff[2]+fff[3]);
    const v2 g40 = fff[0] - fff[1], g41 = fff[2] - fff[3];
    const v2 sg4 = g40 + g41;
    const v2 g5  = g40 - g41;
    const float S   = se.x + se.y;      // no reg sign
    const float P1  = se.x - se.y;      // z6
    const float P3  = sf1.x - sf1.y;    // z6^z7
    const float P7  = sff.x - sff.y;    // z6..z8
    const float PF  = sfff.x - sfff.y;  // z6..z9
    const float PV5 = sg4.x - sg4.y;    // z6..z10
    const float PV6 = g5.x - g5.y;      // z6..z11

    // Z6..Z9: packed 4-value butterfly, lane sign = popc(l) (all 6 lane bits = z0..z5)
    const int pl = __popc(l) & 1;
    float y0 = pl ? -P1 : P1;
    float y1 = pl ? -P3 : P3;
    float y2 = pl ? -P7 : P7;
    float y3 = pl ? -PF : PF;
    y0 += dppx<0xB1>(y0); y1 += dppx<0xB1>(y1);
    y2 += dppx<0xB1>(y2); y3 += dppx<0xB1>(y3);
    y0 += dppx<0x4E>(y0); y1 += dppx<0x4E>(y1);
    y2 += dppx<0x4E>(y2); y3 += dppx<0x4E>(y3);
    const int g = l & 3;
    float y = (g == 0) ? y0 : (g == 1) ? y1 : (g == 2) ? y2 : y3;
    y += swz<0x101F>(y);          // xor 4
    y += swz<0x201F>(y);          // xor 8
    y += swz<0x401F>(y);          // xor 16
    y += __shfl_xor(y, 32, 64);   // xor 32
    // lane 0..3 now hold Z6..Z9

    // Z10: signed full sum of PV5
    float y5 = pl ? -PV5 : PV5;
    y5 += dppx<0xB1>(y5);
    y5 += dppx<0x4E>(y5);
    y5 += swz<0x101F>(y5);
    y5 += swz<0x201F>(y5);
    y5 += swz<0x401F>(y5);
    y5 += __shfl_xor(y5, 32, 64);

    // WHT of S (Z1..Z5 @ lanes 3,7,15,31,63) and PV6 (Z0@62, Z11@63)
    const float sg0 = (l & 1)  ? -1.f : 1.f;
    const float sg1 = (l & 2)  ? -1.f : 1.f;
    const float sg2 = (l & 4)  ? -1.f : 1.f;
    const float sg3 = (l & 8)  ? -1.f : 1.f;
    const float sg4s = (l & 16) ? -1.f : 1.f;
    const float sg5 = (l & 32) ? -1.f : 1.f;
    float wS = S, wV = PV6;
    { const float pS = dppx<0xB1>(wS),  pV = dppx<0xB1>(wV);  wS = __builtin_fmaf(sg0, wS, pS); wV = __builtin_fmaf(sg0, wV, pV); }
    { const float pS = dppx<0x4E>(wS),  pV = dppx<0x4E>(wV);  wS = __builtin_fmaf(sg1, wS, pS); wV = __builtin_fmaf(sg1, wV, pV); }
    { const float pS = swz<0x101F>(wS), pV = swz<0x101F>(wV); wS = __builtin_fmaf(sg2, wS, pS); wV = __builtin_fmaf(sg2, wV, pV); }
    { const float pS = swz<0x201F>(wS), pV = swz<0x201F>(wV); wS = __builtin_fmaf(sg3, wS, pS); wV = __builtin_fmaf(sg3, wV, pV); }
    { const float pS = swz<0x401F>(wS), pV = swz<0x401F>(wV); wS = __builtin_fmaf(sg4s, wS, pS); wV = __builtin_fmaf(sg4s, wV, pV); }
    { const float pS = __shfl_xor(wS, 32, 64), pV = __shfl_xor(wV, 32, 64);
      wS = __builtin_fmaf(sg5, wS, pS); wV = __builtin_fmaf(sg5, wV, pV); }

    // ---- direct predicated stores (no obuf, no second barrier) ----
    float* ob = out + b * NQ;
    if (l < 4)  ob[6 + l] = y;                                  // Z6..Z9
    if (l == 4) ob[10] = y5;                                    // Z10
    if (l >= 3 && ((l & (l + 1)) == 0)) ob[__popc(l) - 1] = wS; // Z1..Z5 @3,7,15,31,63
    if (l == 62) ob[0]  = wV;                                   // Z0
    if (l == 63) ob[11] = wV;                                   // Z11
}

extern "C" void kernel_launch(void* const* d_in, const int* in_sizes, int n_in,
                              void* d_out, int out_size, void* d_ws, size_t ws_size,
                              hipStream_t stream) {
    const float* x  = (const float*)d_in[0];   // (1024, 12) f32
    const float* th = (const float*)d_in[1];   // (2, 12)    f32
    float* out = (float*)d_out;                // (1024, 12) f32
    (void)in_sizes; (void)n_in; (void)out_size; (void)d_ws; (void)ws_size;

    qc_kernel<<<BATCH, 64, 0, stream>>>(x, th, out);   // ONE wave per batch element
}